// Round 1
// baseline (781.035 us; speedup 1.0000x reference)
//
#include <hip/hip_runtime.h>

#define N_NODES 50000
#define N_EDGES 800000
#define DIM 128

// ---------------- CSR build ----------------

// Detect whether edge_index is int64 (odd 32-bit words are all zero since
// values < 50000) or int32. Writes 1 if int64, 0 if int32.
__global__ void detect64_kernel(const int* __restrict__ ei, int* __restrict__ flag) {
    if (threadIdx.x == 0 && blockIdx.x == 0) {
        int o = 0;
        for (int i = 1; i < 64; i += 2) o |= ei[i];
        *flag = (o == 0) ? 1 : 0;
    }
}

__global__ void count_deg_kernel(const int* __restrict__ ei, const int* __restrict__ flag,
                                 int* __restrict__ deg) {
    int e = blockIdx.x * blockDim.x + threadIdx.x;
    if (e < N_EDGES) {
        int is64 = *flag;
        int d = is64 ? ei[2 * (N_EDGES + e)] : ei[N_EDGES + e];
        atomicAdd(&deg[d], 1);
    }
}

__global__ void scan1_kernel(const int* __restrict__ deg, int* __restrict__ incl,
                             int* __restrict__ partials, int n) {
    __shared__ int s[256];
    int tid = threadIdx.x;
    int i = blockIdx.x * 256 + tid;
    int v = (i < n) ? deg[i] : 0;
    s[tid] = v;
    __syncthreads();
    for (int off = 1; off < 256; off <<= 1) {
        int t = (tid >= off) ? s[tid - off] : 0;
        __syncthreads();
        s[tid] += t;
        __syncthreads();
    }
    if (i < n) incl[i] = s[tid];
    if (tid == 255) partials[blockIdx.x] = s[255];
}

__global__ void scan2_kernel(int* __restrict__ partials, int nb) {
    __shared__ int s[256];
    int tid = threadIdx.x;
    int v = (tid < nb) ? partials[tid] : 0;
    s[tid] = v;
    __syncthreads();
    for (int off = 1; off < 256; off <<= 1) {
        int t = (tid >= off) ? s[tid - off] : 0;
        __syncthreads();
        s[tid] += t;
        __syncthreads();
    }
    if (tid < nb) partials[tid] = s[tid] - v;  // exclusive
}

__global__ void scan3_kernel(int* __restrict__ row_ptr /*incl -> excl*/,
                             int* __restrict__ deg_cursor,
                             const int* __restrict__ partials, int n) {
    int i = blockIdx.x * 256 + threadIdx.x;
    if (i < n) {
        int excl = row_ptr[i] - deg_cursor[i] + partials[blockIdx.x];
        row_ptr[i] = excl;
        deg_cursor[i] = excl;  // cursor for fill
    }
    if (i == 0) row_ptr[n] = N_EDGES;
}

__global__ void fill_csr_kernel(const int* __restrict__ ei, const int* __restrict__ flag,
                                int* __restrict__ cursor, int* __restrict__ col_idx) {
    int e = blockIdx.x * blockDim.x + threadIdx.x;
    if (e < N_EDGES) {
        int is64 = *flag;
        int s = is64 ? ei[2 * e] : ei[e];
        int d = is64 ? ei[2 * (N_EDGES + e)] : ei[N_EDGES + e];
        int pos = atomicAdd(&cursor[d], 1);
        col_idx[pos] = s;
    }
}

// ---------------- Aggregation: t[v] = h[v] + sum_{(s->v)} h[s] ----------------
// One wave per node; lane handles 2 floats (float2).
__global__ __launch_bounds__(256) void agg_kernel(const float* __restrict__ h,
                                                  const int* __restrict__ row_ptr,
                                                  const int* __restrict__ col_idx,
                                                  float* __restrict__ t) {
    int w = (blockIdx.x * 256 + threadIdx.x) >> 6;  // global wave id = node
    int lane = threadIdx.x & 63;
    if (w >= N_NODES) return;
    const float2* h2 = (const float2*)h;
    float2 acc = h2[w * 64 + lane];
    int beg = row_ptr[w];
    int end = row_ptr[w + 1];
    for (int j = beg; j < end; ++j) {
        int s = col_idx[j];
        float2 m = h2[s * 64 + lane];
        acc.x += m.x;
        acc.y += m.y;
    }
    ((float2*)t)[w * 64 + lane] = acc;
}

// ---------------- GEMM: C = act(A @ W + bias) (+res) ----------------
// A: (N_NODES,128), W: (128,128) row-major. Block: 256 thr, tile 128 rows x 64 cols.
// W half-panel (32 KB) in LDS; A streamed (16 lanes share each address -> merged).
// Per-thread 8 rows x 4 cols register tile; cols c0+16j -> conflict-free LDS.
template <bool RELU, bool RES>
__global__ __launch_bounds__(256, 4) void gemm128_kernel(const float* __restrict__ A,
                                                         const float* __restrict__ W,
                                                         const float* __restrict__ bias,
                                                         const float* __restrict__ res,
                                                         float* __restrict__ C) {
    __shared__ float Wl[128 * 64];
    const int tid = threadIdx.x;
    const int cbase = blockIdx.y * 64;
    const int R = blockIdx.x * 128;

    // stage W half-panel: 128 rows x 64 cols
    for (int i = tid; i < 128 * 16; i += 256) {
        int k = i >> 4;
        int c4 = (i & 15) << 2;
        *(float4*)&Wl[k * 64 + c4] = *(const float4*)&W[k * 128 + cbase + c4];
    }
    __syncthreads();

    const int c0 = tid & 15;
    const int r0 = (tid >> 4) << 3;

    float acc[8][4];
#pragma unroll
    for (int i = 0; i < 8; ++i)
#pragma unroll
        for (int j = 0; j < 4; ++j) acc[i][j] = 0.0f;

    int rows[8];
#pragma unroll
    for (int i = 0; i < 8; ++i) {
        int r = R + r0 + i;
        if (r > N_NODES - 1) r = N_NODES - 1;  // clamp for loads; stores guarded
        rows[i] = r * DIM;
    }

#pragma unroll 2
    for (int kc = 0; kc < 128; kc += 4) {
        float4 a[8];
#pragma unroll
        for (int i = 0; i < 8; ++i) a[i] = *(const float4*)(A + rows[i] + kc);
#pragma unroll
        for (int kk = 0; kk < 4; ++kk) {
            float wv[4];
#pragma unroll
            for (int j = 0; j < 4; ++j) wv[j] = Wl[(kc + kk) * 64 + c0 + 16 * j];
#pragma unroll
            for (int i = 0; i < 8; ++i) {
                float av = ((const float*)&a[i])[kk];
#pragma unroll
                for (int j = 0; j < 4; ++j) acc[i][j] += av * wv[j];
            }
        }
    }

    float bv[4];
#pragma unroll
    for (int j = 0; j < 4; ++j) bv[j] = bias[cbase + c0 + 16 * j];

#pragma unroll
    for (int i = 0; i < 8; ++i) {
        int r = R + r0 + i;
        if (r < N_NODES) {
#pragma unroll
            for (int j = 0; j < 4; ++j) {
                int col = cbase + c0 + 16 * j;
                float v = acc[i][j] + bv[j];
                if (RELU) v = fmaxf(v, 0.0f);
                if (RES) v += res[r * DIM + col];
                C[r * DIM + col] = v;
            }
        }
    }
}

// ---------------- Launch ----------------

extern "C" void kernel_launch(void* const* d_in, const int* in_sizes, int n_in,
                              void* d_out, int out_size, void* d_ws, size_t ws_size,
                              hipStream_t stream) {
    const float* x = (const float*)d_in[0];
    const int* ei = (const int*)d_in[1];
    const float* w1[3] = {(const float*)d_in[2], (const float*)d_in[6], (const float*)d_in[10]};
    const float* b1[3] = {(const float*)d_in[3], (const float*)d_in[7], (const float*)d_in[11]};
    const float* w2[3] = {(const float*)d_in[4], (const float*)d_in[8], (const float*)d_in[12]};
    const float* b2[3] = {(const float*)d_in[5], (const float*)d_in[9], (const float*)d_in[13]};
    const float* wh = (const float*)d_in[14];
    const float* bh = (const float*)d_in[15];
    float* out = (float*)d_out;

    char* ws = (char*)d_ws;
    const size_t FEAT = (size_t)N_NODES * DIM * sizeof(float);  // 25.6 MB
    float* P = (float*)ws;
    float* Q = (float*)(ws + FEAT);
    int* row_ptr = (int*)(ws + 2 * FEAT);                     // 50001 ints
    int* cursor = (int*)(ws + 2 * FEAT + 200192);             // deg then cursor
    int* col_idx = (int*)(ws + 2 * FEAT + 2 * 200192);        // 800000 ints
    int* partials = (int*)(ws + 2 * FEAT + 2 * 200192 + 3200000);
    int* flag = partials + 256;

    const int SCAN_BLKS = (N_NODES + 255) / 256;  // 196
    const int EDGE_BLKS = (N_EDGES + 255) / 256;

    // ---- CSR build ----
    hipMemsetAsync(cursor, 0, (size_t)N_NODES * sizeof(int), stream);
    detect64_kernel<<<1, 64, 0, stream>>>(ei, flag);
    count_deg_kernel<<<EDGE_BLKS, 256, 0, stream>>>(ei, flag, cursor);
    scan1_kernel<<<SCAN_BLKS, 256, 0, stream>>>(cursor, row_ptr, partials, N_NODES);
    scan2_kernel<<<1, 256, 0, stream>>>(partials, SCAN_BLKS);
    scan3_kernel<<<SCAN_BLKS, 256, 0, stream>>>(row_ptr, cursor, partials, N_NODES);
    fill_csr_kernel<<<EDGE_BLKS, 256, 0, stream>>>(ei, flag, cursor, col_idx);

    dim3 ggrid((N_NODES + 127) / 128, 2);
    const int AGG_BLKS = N_NODES / 4;  // wave per node, 4 waves/block

    // Layer 0: in=x, t->P, u->Q, h1->P (res=x)
    agg_kernel<<<AGG_BLKS, 256, 0, stream>>>(x, row_ptr, col_idx, P);
    gemm128_kernel<true, false><<<ggrid, 256, 0, stream>>>(P, w1[0], b1[0], nullptr, Q);
    gemm128_kernel<false, true><<<ggrid, 256, 0, stream>>>(Q, w2[0], b2[0], x, P);

    // Layer 1: in=P, t->Q, u->out, h2->Q (res=P)
    agg_kernel<<<AGG_BLKS, 256, 0, stream>>>(P, row_ptr, col_idx, Q);
    gemm128_kernel<true, false><<<ggrid, 256, 0, stream>>>(Q, w1[1], b1[1], nullptr, out);
    gemm128_kernel<false, true><<<ggrid, 256, 0, stream>>>(out, w2[1], b2[1], P, Q);

    // Layer 2: in=Q, t->P, u->out, h3->P (no residual)
    agg_kernel<<<AGG_BLKS, 256, 0, stream>>>(Q, row_ptr, col_idx, P);
    gemm128_kernel<true, false><<<ggrid, 256, 0, stream>>>(P, w1[2], b1[2], nullptr, out);
    gemm128_kernel<false, false><<<ggrid, 256, 0, stream>>>(out, w2[2], b2[2], nullptr, P);

    // Head: out = h3 @ wh + bh
    gemm128_kernel<false, false><<<ggrid, 256, 0, stream>>>(P, wh, bh, nullptr, out);
}

// Round 2
// 514.242 us; speedup vs baseline: 1.5188x; 1.5188x over previous
//
#include <hip/hip_runtime.h>

#define N_NODES 50000
#define N_EDGES 800000
#define DIM 128

typedef __attribute__((ext_vector_type(8))) short bf16x8;
typedef __attribute__((ext_vector_type(4))) float f32x4;

// ---------------- CSR build ----------------

__global__ void detect64_kernel(const int* __restrict__ ei, int* __restrict__ flag) {
    if (threadIdx.x == 0 && blockIdx.x == 0) {
        int o = 0;
        for (int i = 1; i < 64; i += 2) o |= ei[i];
        *flag = (o == 0) ? 1 : 0;
    }
}

__global__ void count_deg_kernel(const int* __restrict__ ei, const int* __restrict__ flag,
                                 int* __restrict__ deg) {
    int e = blockIdx.x * blockDim.x + threadIdx.x;
    if (e < N_EDGES) {
        int is64 = *flag;
        int d = is64 ? ei[2 * (N_EDGES + e)] : ei[N_EDGES + e];
        atomicAdd(&deg[d], 1);
    }
}

__global__ void scan1_kernel(const int* __restrict__ deg, int* __restrict__ incl,
                             int* __restrict__ partials, int n) {
    __shared__ int s[256];
    int tid = threadIdx.x;
    int i = blockIdx.x * 256 + tid;
    int v = (i < n) ? deg[i] : 0;
    s[tid] = v;
    __syncthreads();
    for (int off = 1; off < 256; off <<= 1) {
        int t = (tid >= off) ? s[tid - off] : 0;
        __syncthreads();
        s[tid] += t;
        __syncthreads();
    }
    if (i < n) incl[i] = s[tid];
    if (tid == 255) partials[blockIdx.x] = s[255];
}

__global__ void scan2_kernel(int* __restrict__ partials, int nb) {
    __shared__ int s[256];
    int tid = threadIdx.x;
    int v = (tid < nb) ? partials[tid] : 0;
    s[tid] = v;
    __syncthreads();
    for (int off = 1; off < 256; off <<= 1) {
        int t = (tid >= off) ? s[tid - off] : 0;
        __syncthreads();
        s[tid] += t;
        __syncthreads();
    }
    if (tid < nb) partials[tid] = s[tid] - v;  // exclusive
}

__global__ void scan3_kernel(int* __restrict__ row_ptr, int* __restrict__ deg_cursor,
                             const int* __restrict__ partials, int n) {
    int i = blockIdx.x * 256 + threadIdx.x;
    if (i < n) {
        int excl = row_ptr[i] - deg_cursor[i] + partials[blockIdx.x];
        row_ptr[i] = excl;
        deg_cursor[i] = excl;
    }
    if (i == 0) row_ptr[n] = N_EDGES;
}

__global__ void fill_csr_kernel(const int* __restrict__ ei, const int* __restrict__ flag,
                                int* __restrict__ cursor, int* __restrict__ col_idx) {
    int e = blockIdx.x * blockDim.x + threadIdx.x;
    if (e < N_EDGES) {
        int is64 = *flag;
        int s = is64 ? ei[2 * e] : ei[e];
        int d = is64 ? ei[2 * (N_EDGES + e)] : ei[N_EDGES + e];
        int pos = atomicAdd(&cursor[d], 1);
        col_idx[pos] = s;
    }
}

// ---------------- split fp32 -> bf16 hi (trunc) + lo (RNE of residual) ----------------

__device__ __forceinline__ void split8(const float* __restrict__ v, bf16x8& hi, bf16x8& lo) {
#pragma unroll
    for (int j = 0; j < 8; ++j) {
        union { float f; unsigned u; } a;
        a.f = v[j];
        hi[j] = (short)(a.u >> 16);
        union { unsigned u; float f; } hf;
        hf.u = a.u & 0xFFFF0000u;
        union { float f; unsigned u; } r;
        r.f = v[j] - hf.f;
        unsigned ur = r.u + 0x7FFFu + ((r.u >> 16) & 1u);
        lo[j] = (short)(ur >> 16);
    }
}

// ---------------- W prep: fp32 128x128 -> frag-ready bf16 hi/lo planes ----------------
// Output per weight: 64 slots (p*32 + ks*8 + ct), each 64 lanes x 8 shorts (1 KB).
// Frag element: lane l holds W[k = 32*ks + (l>>4)*8 + j][n = 16*ct + (l&15)], j=0..7.

__global__ void prep_w_kernel(const float* __restrict__ w0, const float* __restrict__ w1,
                              const float* __restrict__ w2, const float* __restrict__ w3,
                              const float* __restrict__ w4, const float* __restrict__ w5,
                              const float* __restrict__ w6, short* __restrict__ dst) {
    const float* W;
    switch (blockIdx.x) {
        case 0: W = w0; break;
        case 1: W = w1; break;
        case 2: W = w2; break;
        case 3: W = w3; break;
        case 4: W = w4; break;
        case 5: W = w5; break;
        default: W = w6; break;
    }
    short* d = dst + (size_t)blockIdx.x * 32768;
    for (int idx = threadIdx.x; idx < 16384; idx += 256) {
        int k = idx >> 7, n = idx & 127;
        float w = W[idx];
        union { float f; unsigned u; } a;
        a.f = w;
        short hi = (short)(a.u >> 16);
        union { unsigned u; float f; } hf;
        hf.u = a.u & 0xFFFF0000u;
        union { float f; unsigned u; } r;
        r.f = w - hf.f;
        unsigned ur = r.u + 0x7FFFu + ((r.u >> 16) & 1u);
        short lo = (short)(ur >> 16);
        int ks = k >> 5, q = (k >> 3) & 3, j = k & 7;
        int ct = n >> 4, c = n & 15;
        int lane = q * 16 + c;
        int base = ((ks * 8 + ct) * 64 + lane) * 8 + j;
        d[base] = hi;
        d[16384 + base] = lo;
    }
}

// ---------------- Aggregation: t[v] = h[v] + sum h[src] ----------------
// Half-wave (32 lanes) per node, float4 per lane, unroll-4 for MLP.

__global__ __launch_bounds__(256) void agg_kernel(const float* __restrict__ h,
                                                  const int* __restrict__ row_ptr,
                                                  const int* __restrict__ col_idx,
                                                  float* __restrict__ t) {
    int hw = (blockIdx.x * 256 + threadIdx.x) >> 5;  // node id
    int l = threadIdx.x & 31;
    if (hw >= N_NODES) return;
    const float4* h4 = (const float4*)h;
    float4 a0 = h4[hw * 32 + l];
    float4 a1 = make_float4(0.f, 0.f, 0.f, 0.f);
    float4 a2 = make_float4(0.f, 0.f, 0.f, 0.f);
    float4 a3 = make_float4(0.f, 0.f, 0.f, 0.f);
    int beg = row_ptr[hw], end = row_ptr[hw + 1];
    int j = beg;
    for (; j + 4 <= end; j += 4) {
        int s0 = col_idx[j], s1 = col_idx[j + 1], s2 = col_idx[j + 2], s3 = col_idx[j + 3];
        float4 m0 = h4[s0 * 32 + l];
        float4 m1 = h4[s1 * 32 + l];
        float4 m2 = h4[s2 * 32 + l];
        float4 m3 = h4[s3 * 32 + l];
        a0.x += m0.x; a0.y += m0.y; a0.z += m0.z; a0.w += m0.w;
        a1.x += m1.x; a1.y += m1.y; a1.z += m1.z; a1.w += m1.w;
        a2.x += m2.x; a2.y += m2.y; a2.z += m2.z; a2.w += m2.w;
        a3.x += m3.x; a3.y += m3.y; a3.z += m3.z; a3.w += m3.w;
    }
    for (; j < end; ++j) {
        int s = col_idx[j];
        float4 m = h4[s * 32 + l];
        a0.x += m.x; a0.y += m.y; a0.z += m.z; a0.w += m.w;
    }
    a0.x += a1.x + a2.x + a3.x;
    a0.y += a1.y + a2.y + a3.y;
    a0.z += a1.z + a2.z + a3.z;
    a0.w += a1.w + a2.w + a3.w;
    ((float4*)t)[hw * 32 + l] = a0;
}

// ---------------- GEMM via split-bf16 MFMA ----------------
// C(50000x128) = act(A @ W + bias) (+res). Block: 256 thr, 128 rows x 128 cols.
// Wf: frag-ready bf16 hi/lo planes (prep_w). A: fp32, split in-kernel.
// mfma_f32_16x16x32_bf16: A[m=lane&15][k=(lane>>4)*8+j]; B[k][n=lane&15];
// C col=lane&15, row=(lane>>4)*4+reg.

template <bool RELU, bool RES>
__global__ __launch_bounds__(256, 2) void gemm_mfma_kernel(const float* __restrict__ A,
                                                           const short* __restrict__ Wf,
                                                           const float* __restrict__ bias,
                                                           const float* __restrict__ res,
                                                           float* __restrict__ C) {
    __shared__ short wl[32768];  // 64 KB: 64 slots x 64 lanes x 8 shorts
    const int tid = threadIdx.x;
    const int lane = tid & 63;
    const int wid = tid >> 6;
    const int c = lane & 15;
    const int q = lane >> 4;
    const int R = blockIdx.x * 128;

    // stage all 64 W frag-slots via async global->LDS (16 B per lane)
#pragma unroll
    for (int i = 0; i < 16; ++i) {
        int slot = wid * 16 + i;
        const short* gsrc = Wf + slot * 512 + lane * 8;
        __builtin_amdgcn_global_load_lds(
            (const __attribute__((address_space(1))) void*)gsrc,
            (__attribute__((address_space(3))) void*)&wl[slot * 512], 16, 0, 0);
    }

    int rowIdx[2];
#pragma unroll
    for (int rt = 0; rt < 2; ++rt) {
        int r = R + 32 * wid + 16 * rt + c;
        if (r > N_NODES - 1) r = N_NODES - 1;  // clamp loads; stores guarded
        rowIdx[rt] = r;
    }

    f32x4 acc[2][8];
#pragma unroll
    for (int rt = 0; rt < 2; ++rt)
#pragma unroll
        for (int ct = 0; ct < 8; ++ct) acc[rt][ct] = (f32x4){0.f, 0.f, 0.f, 0.f};

    __syncthreads();  // waits vmcnt(0): LDS staging complete

#pragma unroll
    for (int ks = 0; ks < 4; ++ks) {
        int kb = ks * 32 + q * 8;
        bf16x8 ah[2], al[2];
#pragma unroll
        for (int rt = 0; rt < 2; ++rt) {
            float v[8];
            *(float4*)&v[0] = *(const float4*)(A + (size_t)rowIdx[rt] * DIM + kb);
            *(float4*)&v[4] = *(const float4*)(A + (size_t)rowIdx[rt] * DIM + kb + 4);
            split8(v, ah[rt], al[rt]);
        }
#pragma unroll
        for (int ct = 0; ct < 8; ++ct) {
            bf16x8 bh = *(const bf16x8*)&wl[(ks * 8 + ct) * 512 + lane * 8];
            bf16x8 bl = *(const bf16x8*)&wl[16384 + (ks * 8 + ct) * 512 + lane * 8];
#pragma unroll
            for (int rt = 0; rt < 2; ++rt) {
                acc[rt][ct] = __builtin_amdgcn_mfma_f32_16x16x32_bf16(ah[rt], bh, acc[rt][ct], 0, 0, 0);
                acc[rt][ct] = __builtin_amdgcn_mfma_f32_16x16x32_bf16(al[rt], bh, acc[rt][ct], 0, 0, 0);
                acc[rt][ct] = __builtin_amdgcn_mfma_f32_16x16x32_bf16(ah[rt], bl, acc[rt][ct], 0, 0, 0);
            }
        }
    }

#pragma unroll
    for (int rt = 0; rt < 2; ++rt) {
#pragma unroll
        for (int ct = 0; ct < 8; ++ct) {
            int col = ct * 16 + c;
            float bv = bias[col];
#pragma unroll
            for (int r = 0; r < 4; ++r) {
                int row = R + 32 * wid + 16 * rt + q * 4 + r;
                if (row < N_NODES) {
                    float v = acc[rt][ct][r] + bv;
                    if (RELU) v = fmaxf(v, 0.f);
                    if (RES) v += res[(size_t)row * DIM + col];
                    C[(size_t)row * DIM + col] = v;
                }
            }
        }
    }
}

// ---------------- Launch ----------------

extern "C" void kernel_launch(void* const* d_in, const int* in_sizes, int n_in,
                              void* d_out, int out_size, void* d_ws, size_t ws_size,
                              hipStream_t stream) {
    const float* x = (const float*)d_in[0];
    const int* ei = (const int*)d_in[1];
    const float* w1[3] = {(const float*)d_in[2], (const float*)d_in[6], (const float*)d_in[10]};
    const float* b1[3] = {(const float*)d_in[3], (const float*)d_in[7], (const float*)d_in[11]};
    const float* w2[3] = {(const float*)d_in[4], (const float*)d_in[8], (const float*)d_in[12]};
    const float* b2[3] = {(const float*)d_in[5], (const float*)d_in[9], (const float*)d_in[13]};
    const float* wh = (const float*)d_in[14];
    const float* bh = (const float*)d_in[15];
    float* out = (float*)d_out;

    char* ws = (char*)d_ws;
    const size_t FEAT = (size_t)N_NODES * DIM * sizeof(float);  // 25.6 MB
    float* P = (float*)ws;
    float* Q = (float*)(ws + FEAT);
    int* row_ptr = (int*)(ws + 2 * FEAT);
    int* cursor = (int*)(ws + 2 * FEAT + 200192);
    int* col_idx = (int*)(ws + 2 * FEAT + 2 * 200192);
    int* partials = (int*)(ws + 2 * FEAT + 2 * 200192 + 3200000);
    int* flag = partials + 256;
    short* Wf = (short*)(ws + 2 * FEAT + 2 * 200192 + 3200000 + 4096);  // 7 x 64 KB

    const int SCAN_BLKS = (N_NODES + 255) / 256;
    const int EDGE_BLKS = (N_EDGES + 255) / 256;

    // ---- CSR build + W prep ----
    hipMemsetAsync(cursor, 0, (size_t)N_NODES * sizeof(int), stream);
    detect64_kernel<<<1, 64, 0, stream>>>(ei, flag);
    prep_w_kernel<<<7, 256, 0, stream>>>(w1[0], w2[0], w1[1], w2[1], w1[2], w2[2], wh, Wf);
    count_deg_kernel<<<EDGE_BLKS, 256, 0, stream>>>(ei, flag, cursor);
    scan1_kernel<<<SCAN_BLKS, 256, 0, stream>>>(cursor, row_ptr, partials, N_NODES);
    scan2_kernel<<<1, 256, 0, stream>>>(partials, SCAN_BLKS);
    scan3_kernel<<<SCAN_BLKS, 256, 0, stream>>>(row_ptr, cursor, partials, N_NODES);
    fill_csr_kernel<<<EDGE_BLKS, 256, 0, stream>>>(ei, flag, cursor, col_idx);

    const int GEMM_BLKS = (N_NODES + 127) / 128;  // 391
    const int AGG_BLKS = (N_NODES * 32 + 255) / 256;  // 6250

#define WF(i) (Wf + (size_t)(i) * 32768)

    // Layer 0
    agg_kernel<<<AGG_BLKS, 256, 0, stream>>>(x, row_ptr, col_idx, P);
    gemm_mfma_kernel<true, false><<<GEMM_BLKS, 256, 0, stream>>>(P, WF(0), b1[0], nullptr, Q);
    gemm_mfma_kernel<false, true><<<GEMM_BLKS, 256, 0, stream>>>(Q, WF(1), b2[0], x, P);

    // Layer 1
    agg_kernel<<<AGG_BLKS, 256, 0, stream>>>(P, row_ptr, col_idx, Q);
    gemm_mfma_kernel<true, false><<<GEMM_BLKS, 256, 0, stream>>>(Q, WF(2), b1[1], nullptr, out);
    gemm_mfma_kernel<false, true><<<GEMM_BLKS, 256, 0, stream>>>(out, WF(3), b2[1], P, Q);

    // Layer 2 (no residual)
    agg_kernel<<<AGG_BLKS, 256, 0, stream>>>(Q, row_ptr, col_idx, P);
    gemm_mfma_kernel<true, false><<<GEMM_BLKS, 256, 0, stream>>>(P, WF(4), b1[2], nullptr, out);
    gemm_mfma_kernel<false, false><<<GEMM_BLKS, 256, 0, stream>>>(out, WF(5), b2[2], nullptr, P);

    // Head
    gemm_mfma_kernel<false, false><<<GEMM_BLKS, 256, 0, stream>>>(P, WF(6), bh, nullptr, out);
#undef WF
}